// Round 11
// baseline (104.809 us; speedup 1.0000x reference)
//
#include <hip/hip_runtime.h>

// CVXPolicy_Quadcopter: fused MLP (13->100 tanh ->12) + closed-form argmin via
// Lambert W. R10: 1 element/thread (7.6 waves/SIMD of TLP) + dot2 f16 MACs +
// MANUAL 1-deep weight prefetch (next jp's rows loaded into wave-uniform vars
// -> SGPRs before computing current jp), zero-padded extra row so no guard.
// ws layout (uint32 dwords, built by pack_weights):
//   region A [0..815]: per unit-pair jp in [0,50] (16 dw; jp=50 is zeros):
//     dw 0..6  : half2 W1' k-pairs (k=2s,2s+1; k=13 pad=0) for unit 2jp
//     dw 7..13 : same for unit 2jp+1
//     dw 14,15 : float b1'[2jp], b1'[2jp+1]
//     (W1', b1' pre-scaled by 2*log2e so tanh uses exp2 with no multiply)
//   region B [816..1223]: per jp in [0,50] (8 dw; jp=50 zeros): dw m=0..5:
//     half2 {W2[2jp][6+m], W2[2jp+1][6+m]}; dw 6,7 pad

constexpr int S = 12;   // z features
constexpr int H = 100;  // hidden
#define TWO_LOG2E 2.8853900817779268f
#define REG_B 816

typedef _Float16 h2 __attribute__((ext_vector_type(2)));

__device__ __forceinline__ float fast_rcp(float x) {
    return __builtin_amdgcn_rcpf(x);
}

__device__ __forceinline__ h2 bit_h2(unsigned int u) {
    union { unsigned int u; h2 h; } cv; cv.u = u; return cv.h;
}

#if __has_builtin(__builtin_amdgcn_fdot2)
__device__ __forceinline__ float fdot2(h2 a, h2 b, float c) {
    return __builtin_amdgcn_fdot2(a, b, c, false);
}
#else
__device__ __forceinline__ float fdot2(h2 a, h2 b, float c) {
    return fmaf((float)a.x, (float)b.x, fmaf((float)a.y, (float)b.y, c));
}
#endif

__device__ __forceinline__ h2 pk16(float a, float b) {
#if __has_builtin(__builtin_amdgcn_cvt_pkrtz)
    union {
        __fp16 __attribute__((ext_vector_type(2))) f;
        h2 h;
    } cv;
    cv.f = __builtin_amdgcn_cvt_pkrtz(a, b);
    return cv.h;
#else
    h2 r; r.x = (_Float16)a; r.y = (_Float16)b; return r;
#endif
}

__global__ __launch_bounds__(256) void pack_weights(
    const float* __restrict__ W1, const float* __restrict__ b1,
    const float* __restrict__ W2, unsigned int* __restrict__ ws)
{
    int idx = blockIdx.x * 256 + threadIdx.x;
    if (idx < REG_B) {                        // region A (51 rows x 16 dw)
        int jp = idx >> 4, s = idx & 15;
        unsigned int v = 0;
        if (jp < 50) {
            if (s < 14) {
                int unit = 2 * jp + (s >= 7);
                int q = (s < 7) ? s : s - 7;
                int k0 = 2 * q, k1 = 2 * q + 1;
                float w0 = W1[k0 * H + unit] * TWO_LOG2E;
                float w1 = (k1 < 13) ? W1[k1 * H + unit] * TWO_LOG2E : 0.0f;
                union { h2 h; unsigned int u; } cv;
                cv.h = pk16(w0, w1);
                v = cv.u;
            } else {
                int unit = 2 * jp + (s - 14);
                union { float f; unsigned int u; } cv;
                cv.f = b1[unit] * TWO_LOG2E;
                v = cv.u;
            }
        }
        ws[idx] = v;
    } else if (idx < REG_B + 408) {           // region B (51 rows x 8 dw)
        int r = idx - REG_B;
        int jp = r >> 3, m = r & 7;
        unsigned int v = 0;
        if (jp < 50 && m < 6) {
            float w0 = W2[(2 * jp) * S + 6 + m];
            float w1 = W2[(2 * jp + 1) * S + 6 + m];
            union { h2 h; unsigned int u; } cv;
            cv.h = pk16(w0, w1);
            v = cv.u;
        }
        ws[idx] = v;
    }
}

__global__ __launch_bounds__(256) void cvx_quad_kernel(
    const float* __restrict__ z, const float* __restrict__ t,
    const unsigned int* __restrict__ ws, const float* __restrict__ b2,
    float* __restrict__ out, int B)
{
    int i = blockIdx.x * 256 + threadIdx.x;
    if (i >= B) return;

    // ---- load input row, convert to half2 k-pairs once ----
    h2 in[7];
    {
        const float4* zr = reinterpret_cast<const float4*>(z) + (size_t)i * 3;
        float4 a0 = zr[0], a1 = zr[1], a2 = zr[2];
        in[0] = pk16(t[i], a0.x);
        in[1] = pk16(a0.y, a0.z);
        in[2] = pk16(a0.w, a1.x);
        in[3] = pk16(a1.y, a1.z);
        in[4] = pk16(a1.w, a2.x);
        in[5] = pk16(a2.y, a2.z);
        in[6] = pk16(a2.w, 0.0f);
    }

    float p[6];
    #pragma unroll
    for (int m = 0; m < 6; ++m) p[m] = b2[6 + m];

    const uint4* A4 = reinterpret_cast<const uint4*>(ws);          // 4/row
    const uint4* B4 = reinterpret_cast<const uint4*>(ws + REG_B);  // 2/row

    // preload jp=0 (wave-uniform -> s_load_dwordx4)
    uint4 a0 = A4[0], a1 = A4[1], a2 = A4[2], a3 = A4[3];
    uint4 r0 = B4[0], r1 = B4[1];

    #pragma unroll 2
    for (int jp = 0; jp < H / 2; ++jp) {
        // ---- prefetch jp+1 (row 50 is zeros; no guard needed) ----
        uint4 na0 = A4[(jp + 1) * 4 + 0];
        uint4 na1 = A4[(jp + 1) * 4 + 1];
        uint4 na2 = A4[(jp + 1) * 4 + 2];
        uint4 na3 = A4[(jp + 1) * 4 + 3];
        uint4 nr0 = B4[(jp + 1) * 2 + 0];
        uint4 nr1 = B4[(jp + 1) * 2 + 1];

        // ---- layer 1: two hidden units via 14 dot2 ----
        float acc0 = __uint_as_float(a3.z);   // b1'[2jp]
        float acc1 = __uint_as_float(a3.w);   // b1'[2jp+1]
        acc0 = fdot2(in[0], bit_h2(a0.x), acc0);
        acc0 = fdot2(in[1], bit_h2(a0.y), acc0);
        acc0 = fdot2(in[2], bit_h2(a0.z), acc0);
        acc0 = fdot2(in[3], bit_h2(a0.w), acc0);
        acc0 = fdot2(in[4], bit_h2(a1.x), acc0);
        acc0 = fdot2(in[5], bit_h2(a1.y), acc0);
        acc0 = fdot2(in[6], bit_h2(a1.z), acc0);
        acc1 = fdot2(in[0], bit_h2(a1.w), acc1);
        acc1 = fdot2(in[1], bit_h2(a2.x), acc1);
        acc1 = fdot2(in[2], bit_h2(a2.y), acc1);
        acc1 = fdot2(in[3], bit_h2(a2.z), acc1);
        acc1 = fdot2(in[4], bit_h2(a2.w), acc1);
        acc1 = fdot2(in[5], bit_h2(a3.x), acc1);
        acc1 = fdot2(in[6], bit_h2(a3.y), acc1);

        // ---- tanh pair, shared rcp:  th = 1 - 2/(1+e),  e = 2^acc ----
        float e0 = 1.0f + __builtin_amdgcn_exp2f(acc0);
        float e1 = 1.0f + __builtin_amdgcn_exp2f(acc1);
        float s  = -2.0f * fast_rcp(e0 * e1);
        float th0 = fmaf(e1, s, 1.0f);
        float th1 = fmaf(e0, s, 1.0f);
        h2 th = pk16(th0, th1);

        // ---- layer 2: 6 dot2 ----
        p[0] = fdot2(th, bit_h2(r0.x), p[0]);
        p[1] = fdot2(th, bit_h2(r0.y), p[1]);
        p[2] = fdot2(th, bit_h2(r0.z), p[2]);
        p[3] = fdot2(th, bit_h2(r0.w), p[3]);
        p[4] = fdot2(th, bit_h2(r1.x), p[4]);
        p[5] = fdot2(th, bit_h2(r1.y), p[5]);

        a0 = na0; a1 = na1; a2 = na2; a3 = na3;
        r0 = nr0; r1 = nr1;
    }

    float c0 = 2.0f * (p[0] + p[1] + p[2]);  // / MASS, MASS = 0.5
    float c1 = p[3], c2 = p[4], c3 = p[5];
    float x = fmaf(c0, c0, fmaf(c1, c1, fmaf(c2, c2, c3 * c3)));

    // Lambert W: solve w e^w = x, Newton from w0 = log(1+x)
    float w = __logf(1.0f + x);
    #pragma unroll
    for (int it = 0; it < 5; ++it) {
        float ew  = __expf(w);
        float num = fmaf(w, ew, -x);        // w*e^w - x
        float den = fmaf(ew, w, ew);        // e^w * (w + 1)
        w = w - num * fast_rcp(den);
    }

    float sc = -__expf(-0.5f * w);
    float4 o;
    o.x = c0 * sc;
    o.y = c1 * sc;
    o.z = c2 * sc;
    o.w = c3 * sc;
    reinterpret_cast<float4*>(out)[i] = o;
}

extern "C" void kernel_launch(void* const* d_in, const int* in_sizes, int n_in,
                              void* d_out, int out_size, void* d_ws, size_t ws_size,
                              hipStream_t stream) {
    const float* z  = (const float*)d_in[0];
    const float* t  = (const float*)d_in[1];
    const float* W1 = (const float*)d_in[2];
    const float* b1 = (const float*)d_in[3];
    const float* W2 = (const float*)d_in[4];
    const float* b2 = (const float*)d_in[5];
    float* out = (float*)d_out;
    unsigned int* ws = (unsigned int*)d_ws;   // needs 1224 dwords = 4.9 KB

    pack_weights<<<dim3(5), dim3(256), 0, stream>>>(W1, b1, W2, ws);

    int B = in_sizes[1];  // t has B elements
    int grid = (B + 255) / 256;
    cvx_quad_kernel<<<dim3(grid), dim3(256), 0, stream>>>(z, t, ws, b2, out, B);
}